// Round 4
// baseline (3292.643 us; speedup 1.0000x reference)
//
#include <hip/hip_runtime.h>
#include <hip/hip_bf16.h>
#include <math.h>

// ---------------------------------------------------------------------------
// CustomAutoencoder forward, fp32.
// Encoder (NCHW) + FC unchanged from r3 (passed). Decoder rewritten:
//   - NHWC intermediates d1,d2,d3
//   - thread = input pixel -> 2x2 output quad (all parities fused)
//   - weights repacked to [e][ic][ocp], read at wave-uniform addresses
//     (scalarized to s_load -> SGPR operands, no LDS)
// ConvT gather quad table (verified in r3's deconv_full):
//   e:     0     1     2     3     4     5     6     7     8
//   in:  (0,0) (0,0) (0,0) (0,0) (0,1) (0,1) (1,0) (1,0) (1,1)
//   out: (0,0) (0,1) (1,0) (1,1) (0,1) (1,1) (1,0) (1,1) (1,1)
//   tap:  4     5     7     8     3     6     1     2     0      (ky*3+kx)
// ---------------------------------------------------------------------------

__device__ __constant__ int cEDY[9] = {0, 0, 0, 0, 0, 0, 1, 1, 1};
__device__ __constant__ int cEDX[9] = {0, 0, 0, 0, 1, 1, 0, 0, 1};

// ------------------------------ conv k3 s2 p1 + relu -----------------------
template <int IC, int OC, int IH, int IW>
__global__ __launch_bounds__(256) void conv_k(const float* __restrict__ x,
                                              const float* __restrict__ w,
                                              const float* __restrict__ b,
                                              float* __restrict__ y, int B) {
    constexpr int OH = IH / 2, OW = IW / 2;
    __shared__ float wlds[IC * 9 * OC];
    for (int t = threadIdx.x; t < IC * 9 * OC; t += blockDim.x) {
        int oc = t % OC;
        int r = t / OC;
        int tap = r % 9;
        int ic = r / 9;
        wlds[t] = w[(oc * IC + ic) * 9 + tap];
    }
    __syncthreads();

    int idx = blockIdx.x * blockDim.x + threadIdx.x;
    if (idx >= B * OH * OW) return;
    int ox = idx % OW;
    int t2 = idx / OW;
    int oy = t2 % OH;
    int n = t2 / OH;

    const float* xn = x + (size_t)n * IC * IH * IW;
    float acc[OC];
#pragma unroll
    for (int oc = 0; oc < OC; oc++) acc[oc] = b[oc];

#pragma unroll 2
    for (int ic = 0; ic < IC; ic++) {
        float xv[9];
#pragma unroll
        for (int ky = 0; ky < 3; ky++) {
            int iy = 2 * oy - 1 + ky;
#pragma unroll
            for (int kx = 0; kx < 3; kx++) {
                int ix = 2 * ox - 1 + kx;
                bool ok = (iy >= 0) && (iy < IH) && (ix >= 0) && (ix < IW);
                xv[ky * 3 + kx] = ok ? xn[((size_t)ic * IH + iy) * IW + ix] : 0.f;
            }
        }
#pragma unroll
        for (int t3 = 0; t3 < 9; t3++) {
            if constexpr (OC % 4 == 0) {
                const float4* wr = (const float4*)(wlds + ((size_t)ic * 9 + t3) * OC);
#pragma unroll
                for (int o4 = 0; o4 < OC / 4; o4++) {
                    float4 wv = wr[o4];
                    acc[4 * o4 + 0] = fmaf(xv[t3], wv.x, acc[4 * o4 + 0]);
                    acc[4 * o4 + 1] = fmaf(xv[t3], wv.y, acc[4 * o4 + 1]);
                    acc[4 * o4 + 2] = fmaf(xv[t3], wv.z, acc[4 * o4 + 2]);
                    acc[4 * o4 + 3] = fmaf(xv[t3], wv.w, acc[4 * o4 + 3]);
                }
            } else {
#pragma unroll
                for (int oc = 0; oc < OC; oc++)
                    acc[oc] = fmaf(xv[t3], wlds[(ic * 9 + t3) * OC + oc], acc[oc]);
            }
        }
    }
    float* yn = y + (size_t)n * OC * OH * OW + (size_t)oy * OW + ox;
#pragma unroll
    for (int oc = 0; oc < OC; oc++) yn[(size_t)oc * OH * OW] = fmaxf(acc[oc], 0.f);
}

// --------------------- weight repack: [ic][oc][3][3] -> [9][IC][OCP] -------
template <int IC, int OC, int OCP>
__global__ __launch_bounds__(256) void repack_k(const float* __restrict__ w,
                                                float* __restrict__ dst) {
    constexpr int ETAP[9] = {4, 5, 7, 8, 3, 6, 1, 2, 0};
    int idx = blockIdx.x * blockDim.x + threadIdx.x;
    if (idx >= 9 * IC * OCP) return;
    int oc = idx % OCP;
    int ic = (idx / OCP) % IC;
    int e = idx / (OCP * IC);
    dst[idx] = (oc < OC) ? w[((size_t)(ic * OC + oc)) * 9 + ETAP[e]] : 0.f;
}

// ------------- deconv quad kernel: NHWC (or NCHW-in for dc1) ---------------
// OCF: full repacked oc width; OCH: oc handled per block (ocb = blockIdx.y*OCH)
// OCR: real oc count (bias/store guard); XNCHW: input layout; YNCHW: out layout
template <int IC, int OCF, int OCH, int OCR, int IH, int XNCHW, int YNCHW>
__global__ __launch_bounds__(256) void deconv_q(const float* __restrict__ x,
                                                const float* __restrict__ wrep,
                                                const float* __restrict__ bias,
                                                float* __restrict__ y, int B) {
    constexpr int IW = IH, OH = 2 * IH, OW = 2 * IH;
    int idx = blockIdx.x * blockDim.x + threadIdx.x;
    if (idx >= B * IH * IW) return;
    int j = idx % IW;
    int t2 = idx / IW;
    int i = t2 % IH;
    int n = t2 / IH;
    const int ocb = blockIdx.y * OCH;

    float acc[2][2][OCH];
#pragma unroll
    for (int oc = 0; oc < OCH; oc++) {
        float bv = (ocb + oc < OCR) ? bias[ocb + oc] : 0.f;
        acc[0][0][oc] = bv;
        acc[0][1][oc] = bv;
        acc[1][0][oc] = bv;
        acc[1][1][oc] = bv;
    }
    const bool jok = (j + 1 < IW);
    const bool iok = (i + 1 < IH);
    const bool ok11 = iok && jok;

    const float4* wr4 = (const float4*)wrep;

#pragma unroll 4
    for (int ic = 0; ic < IC; ic++) {
        float xq[2][2];
        if constexpr (XNCHW) {
            const float* xp = x + ((size_t)(n * IC + ic) * IH + i) * IW + j;
            xq[0][0] = xp[0];
            xq[0][1] = jok ? xp[1] : 0.f;
            xq[1][0] = iok ? xp[IW] : 0.f;
            xq[1][1] = ok11 ? xp[IW + 1] : 0.f;
        } else {
            // NHWC: load float4 of channels at ic%4==0, then extract
            static_assert(IC % 4 == 0, "NHWC path needs IC%4==0");
            const int c = ic & 3;
            const int ic4 = ic >> 2;
            const float4* xb = (const float4*)(x) + ((size_t)(n * IH + i) * IW + j) * (IC / 4);
            // (re)load quad float4s each ic4 boundary; compiler folds c via unroll-4
            float4 q00 = xb[ic4];
            float4 q01 = jok ? xb[(size_t)(IC / 4) + ic4] : make_float4(0, 0, 0, 0);
            float4 q10 = iok ? xb[(size_t)IW * (IC / 4) + ic4] : make_float4(0, 0, 0, 0);
            float4 q11 = ok11 ? xb[(size_t)(IW + 1) * (IC / 4) + ic4] : make_float4(0, 0, 0, 0);
            xq[0][0] = (c == 0) ? q00.x : (c == 1) ? q00.y : (c == 2) ? q00.z : q00.w;
            xq[0][1] = (c == 0) ? q01.x : (c == 1) ? q01.y : (c == 2) ? q01.z : q01.w;
            xq[1][0] = (c == 0) ? q10.x : (c == 1) ? q10.y : (c == 2) ? q10.z : q10.w;
            xq[1][1] = (c == 0) ? q11.x : (c == 1) ? q11.y : (c == 2) ? q11.z : q11.w;
        }
        constexpr int EDY[9] = {0, 0, 0, 0, 0, 0, 1, 1, 1};
        constexpr int EDX[9] = {0, 0, 0, 0, 1, 1, 0, 0, 1};
        constexpr int ERY[9] = {0, 0, 1, 1, 0, 1, 1, 1, 1};
        constexpr int ERX[9] = {0, 1, 0, 1, 1, 1, 0, 1, 1};
#pragma unroll
        for (int e = 0; e < 9; e++) {
            float xs = xq[EDY[e]][EDX[e]];
            // wave-uniform weight address -> s_load, SGPR operands
            const float4* wrow = wr4 + ((size_t)(e * IC + ic) * OCF + ocb) / 4;
#pragma unroll
            for (int q = 0; q < OCH / 4; q++) {
                float4 wv = wrow[q];
                acc[ERY[e]][ERX[e]][4 * q + 0] = fmaf(xs, wv.x, acc[ERY[e]][ERX[e]][4 * q + 0]);
                acc[ERY[e]][ERX[e]][4 * q + 1] = fmaf(xs, wv.y, acc[ERY[e]][ERX[e]][4 * q + 1]);
                acc[ERY[e]][ERX[e]][4 * q + 2] = fmaf(xs, wv.z, acc[ERY[e]][ERX[e]][4 * q + 2]);
                acc[ERY[e]][ERX[e]][4 * q + 3] = fmaf(xs, wv.w, acc[ERY[e]][ERX[e]][4 * q + 3]);
            }
        }
    }

    if constexpr (YNCHW) {
        // NCHW out (final layer): per oc<OCR, 2 rows x float2
#pragma unroll
        for (int oc = 0; oc < OCR; oc++) {
            float* yp = y + ((size_t)(n * OCR + oc) * OH + 2 * i) * OW + 2 * j;
            *reinterpret_cast<float2*>(yp) = make_float2(acc[0][0][oc], acc[0][1][oc]);
            *reinterpret_cast<float2*>(yp + OW) = make_float2(acc[1][0][oc], acc[1][1][oc]);
        }
    } else {
        // NHWC out: 4 pixels x OCH contiguous floats at channel offset ocb
#pragma unroll
        for (int dy = 0; dy < 2; dy++)
#pragma unroll
            for (int dx = 0; dx < 2; dx++) {
                float* yp = y + ((size_t)(n * OH + 2 * i + dy) * OW + (2 * j + dx)) * OCF + ocb;
#pragma unroll
                for (int q = 0; q < OCH / 4; q++)
                    *reinterpret_cast<float4*>(yp + 4 * q) =
                        make_float4(acc[dy][dx][4 * q + 0], acc[dy][dx][4 * q + 1],
                                    acc[dy][dx][4 * q + 2], acc[dy][dx][4 * q + 3]);
            }
    }
}

// ------------------------------ linear (+act) ------------------------------
template <int IN, int OUT, int ACT>  // ACT: 0 relu, 1 leaky(0.01)
__global__ __launch_bounds__(256) void linear_k(const float* __restrict__ h,
                                                const float* __restrict__ w,
                                                const float* __restrict__ b,
                                                float* __restrict__ y, int B) {
    int idx = blockIdx.x * blockDim.x + threadIdx.x;
    if (idx >= B * OUT) return;
    int o = idx % OUT;
    int n = idx / OUT;
    const float4* hr = (const float4*)(h + (size_t)n * IN);
    const float4* wr = (const float4*)(w + (size_t)o * IN);
    float acc = 0.f;
#pragma unroll 4
    for (int k = 0; k < IN / 4; k++) {
        float4 a = hr[k];
        float4 ww = wr[k];
        acc += a.x * ww.x + a.y * ww.y + a.z * ww.z + a.w * ww.w;
    }
    acc += b[o];
    y[idx] = (ACT == 0) ? fmaxf(acc, 0.f) : (acc > 0.f ? acc : 0.01f * acc);
}

// --------------------- CustomLayer: lin + tanh neuron ----------------------
__global__ __launch_bounds__(256) void custom_layer_k(
    const float* __restrict__ h, const float* __restrict__ clw, const float* __restrict__ clb,
    const float* __restrict__ nw, const float* __restrict__ nb, const float* __restrict__ low,
    const float* __restrict__ high, float* __restrict__ y, int B) {
    int idx = blockIdx.x * blockDim.x + threadIdx.x;
    if (idx >= B * 512) return;
    int o = idx % 512;
    int n = idx / 512;
    const float4* hr = (const float4*)(h + (size_t)n * 256);
    const float4* w1 = (const float4*)(clw + (size_t)o * 256);
    const float4* w2 = (const float4*)(nw + (size_t)o * 256);
    float lin = 0.f, z = 0.f;
#pragma unroll 4
    for (int k = 0; k < 64; k++) {
        float4 a = hr[k];
        float4 b1 = w1[k];
        float4 b2 = w2[k];
        lin += a.x * b1.x + a.y * b1.y + a.z * b1.z + a.w * b1.w;
        z += a.x * b2.x + a.y * b2.y + a.z * b2.z + a.w * b2.w;
    }
    lin += clb[o];
    z += nb[o];
    float neur = tanhf(tanhf(low[o] * z - high[o]));
    y[idx] = fmaxf(lin + neur, 0.f);
}

// ---------------------------------------------------------------------------
extern "C" void kernel_launch(void* const* d_in, const int* in_sizes, int n_in,
                              void* d_out, int out_size, void* d_ws, size_t ws_size,
                              hipStream_t stream) {
    const float* x = (const float*)d_in[0];
    const float* conv1_w = (const float*)d_in[1];
    const float* conv1_b = (const float*)d_in[2];
    const float* conv2_w = (const float*)d_in[3];
    const float* conv2_b = (const float*)d_in[4];
    const float* conv3_w = (const float*)d_in[5];
    const float* conv3_b = (const float*)d_in[6];
    const float* conv4_w = (const float*)d_in[7];
    const float* conv4_b = (const float*)d_in[8];
    const float* l2_w = (const float*)d_in[9];
    const float* l2_b = (const float*)d_in[10];
    const float* cl_w = (const float*)d_in[11];
    const float* cl_b = (const float*)d_in[12];
    const float* n_w = (const float*)d_in[13];
    const float* n_b = (const float*)d_in[14];
    const float* low = (const float*)d_in[15];
    const float* high = (const float*)d_in[16];
    const float* l4_w = (const float*)d_in[17];
    const float* l4_b = (const float*)d_in[18];
    const float* lL_w = (const float*)d_in[19];
    const float* lL_b = (const float*)d_in[20];
    const float* fc4_w = (const float*)d_in[21];
    const float* fc4_b = (const float*)d_in[22];
    const float* fc5_w = (const float*)d_in[23];
    const float* fc5_b = (const float*)d_in[24];
    const float* dc1_w = (const float*)d_in[25];
    const float* dc1_b = (const float*)d_in[26];
    const float* dc2_w = (const float*)d_in[27];
    const float* dc2_b = (const float*)d_in[28];
    const float* dc3_w = (const float*)d_in[29];
    const float* dc3_b = (const float*)d_in[30];
    const float* dc4_w = (const float*)d_in[31];
    const float* dc4_b = (const float*)d_in[32];

    const int B = in_sizes[0] / (3 * 128 * 128);  // 256
    float* out = (float*)d_out;
    float* ws = (float*)d_ws;
    const size_t WS = ws_size / sizeof(float);

    // --- repacked decoder weights at front ---
    float* rp1 = ws;               // [9][8][16]  = 1152
    float* rp2 = rp1 + 1152;       // [9][16][32] = 4608
    float* rp3 = rp2 + 4608;       // [9][32][64] = 18432
    float* rp4 = rp3 + 18432;      // [9][64][4]  = 2304
    const size_t repsz = 26496;

    // --- persistent small FC buffers ---
    float* h4 = ws + repsz;              // [B,128]
    float* h5 = h4 + (size_t)B * 128;    // [B,256]
    float* h6 = h5 + (size_t)B * 256;    // [B,512]
    float* h7 = h6 + (size_t)B * 512;    // [B,256]
    float* h8 = h7 + (size_t)B * 256;    // [B,256]
    float* h9 = h8 + (size_t)B * 256;    // [B,512]
    float* h10 = h9 + (size_t)B * 512;   // [B,512]
    const size_t small = (size_t)B * 2432;

    // --- pick largest chunk size C: need = repsz + small + C*331776 ---
    int C = 1;
    for (int cand = B; cand >= 1; cand >>= 1) {
        if (repsz + small + (size_t)cand * 331776 <= WS) { C = cand; break; }
        if (cand == 1) break;
    }
    float* bufC = ws + repsz + small;           // C*4096   (h3 / d1-NHWC)
    float* bufA = bufC + (size_t)C * 4096;      // C*65536  (h1 / d2-NHWC)
    float* bufB = bufA + (size_t)C * 65536;     // C*262144 (h2 / d3-NHWC)

    dim3 blk(256);
    auto cdiv = [](int a, int b) { return (a + b - 1) / b; };

    // ---------------- weight repack (once per launch) ----------------
    repack_k<8, 16, 16><<<dim3(cdiv(9 * 8 * 16, 256)), blk, 0, stream>>>(dc1_w, rp1);
    repack_k<16, 32, 32><<<dim3(cdiv(9 * 16 * 32, 256)), blk, 0, stream>>>(dc2_w, rp2);
    repack_k<32, 64, 64><<<dim3(cdiv(9 * 32 * 64, 256)), blk, 0, stream>>>(dc3_w, rp3);
    repack_k<64, 3, 4><<<dim3(cdiv(9 * 64 * 4, 256)), blk, 0, stream>>>(dc4_w, rp4);

    // ---------------- encoder, chunked (NCHW, unchanged) ----------------
    for (int n0 = 0; n0 < B; n0 += C) {
        int Cc = (B - n0 < C) ? (B - n0) : C;
        conv_k<3, 16, 128, 128><<<dim3(cdiv(Cc * 64 * 64, 256)), blk, 0, stream>>>(
            x + (size_t)n0 * 3 * 128 * 128, conv1_w, conv1_b, bufA, Cc);
        conv_k<16, 8, 64, 64><<<dim3(cdiv(Cc * 32 * 32, 256)), blk, 0, stream>>>(
            bufA, conv2_w, conv2_b, bufB, Cc);
        conv_k<8, 4, 32, 32><<<dim3(cdiv(Cc * 16 * 16, 256)), blk, 0, stream>>>(
            bufB, conv3_w, conv3_b, bufC, Cc);
        conv_k<4, 2, 16, 16><<<dim3(cdiv(Cc * 8 * 8, 256)), blk, 0, stream>>>(
            bufC, conv4_w, conv4_b, h4 + (size_t)n0 * 128, Cc);
    }

    // ---------------- FC chain, full batch ----------------
    linear_k<128, 256, 0><<<dim3(cdiv(B * 256, 256)), blk, 0, stream>>>(h4, l2_w, l2_b, h5, B);
    custom_layer_k<<<dim3(cdiv(B * 512, 256)), blk, 0, stream>>>(h5, cl_w, cl_b, n_w, n_b, low,
                                                                 high, h6, B);
    linear_k<512, 256, 0><<<dim3(cdiv(B * 256, 256)), blk, 0, stream>>>(h6, l4_w, l4_b, h7, B);
    linear_k<256, 256, 1><<<dim3(cdiv(B * 256, 256)), blk, 0, stream>>>(h7, lL_w, lL_b, h8, B);
    linear_k<256, 512, 1><<<dim3(cdiv(B * 512, 256)), blk, 0, stream>>>(h8, fc4_w, fc4_b, h9, B);
    linear_k<512, 512, 0><<<dim3(cdiv(B * 512, 256)), blk, 0, stream>>>(h9, fc5_w, fc5_b, h10, B);

    // ---------------- decoder, chunked (NHWC quad kernels) ----------------
    for (int n0 = 0; n0 < B; n0 += C) {
        int Cc = (B - n0 < C) ? (B - n0) : C;
        // dc1: NCHW in [Cc,8,8,8] -> NHWC d1 [Cc,16,16,16ch]
        deconv_q<8, 16, 16, 16, 8, 1, 0><<<dim3(cdiv(Cc * 64, 256)), blk, 0, stream>>>(
            h10 + (size_t)n0 * 512, rp1, dc1_b, bufC, Cc);
        // dc2: NHWC -> NHWC d2 [Cc,32,32,32ch]
        deconv_q<16, 32, 32, 32, 16, 0, 0><<<dim3(cdiv(Cc * 256, 256)), blk, 0, stream>>>(
            bufC, rp2, dc2_b, bufA, Cc);
        // dc3: NHWC -> NHWC d3 [Cc,64,64,64ch], oc halves via grid.y
        deconv_q<32, 64, 32, 64, 32, 0, 0><<<dim3(cdiv(Cc * 1024, 256), 2), blk, 0, stream>>>(
            bufA, rp3, dc3_b, bufB, Cc);
        // dc4: NHWC -> NCHW out [Cc,3,128,128]
        deconv_q<64, 4, 4, 3, 64, 0, 1><<<dim3(cdiv(Cc * 4096, 256)), blk, 0, stream>>>(
            bufB, rp4, dc4_b, out + (size_t)n0 * 3 * 128 * 128, Cc);
    }
}

// Round 5
// 864.713 us; speedup vs baseline: 3.8078x; 3.8078x over previous
//
#include <hip/hip_runtime.h>
#include <hip/hip_bf16.h>
#include <math.h>

// ---------------------------------------------------------------------------
// CustomAutoencoder forward, fp32.
// r5: r3's verified kernels, minus chunk-starvation; dc3 rewritten as
// wave-per-row / lane=oc (no LDS, coalesced lane weights, uniform x rows).
// ConvT gather: out[oy][ox] += x[(oy+1-ky)/2][(ox+1-kx)/2] * w[ic][oc][ky][kx]
//   out row 2i   <- ky=1 @ x row i
//   out row 2i+1 <- ky=2 @ x row i,  ky=0 @ x row i+1   (cols identical w/ kx)
// ---------------------------------------------------------------------------

// ------------------------------ conv k3 s2 p1 + relu -----------------------
template <int IC, int OC, int IH, int IW>
__global__ __launch_bounds__(256) void conv_k(const float* __restrict__ x,
                                              const float* __restrict__ w,
                                              const float* __restrict__ b,
                                              float* __restrict__ y, int B) {
    constexpr int OH = IH / 2, OW = IW / 2;
    __shared__ float wlds[IC * 9 * OC];
    for (int t = threadIdx.x; t < IC * 9 * OC; t += blockDim.x) {
        int oc = t % OC;
        int r = t / OC;
        int tap = r % 9;
        int ic = r / 9;
        wlds[t] = w[(oc * IC + ic) * 9 + tap];
    }
    __syncthreads();

    int idx = blockIdx.x * blockDim.x + threadIdx.x;
    if (idx >= B * OH * OW) return;
    int ox = idx % OW;
    int t2 = idx / OW;
    int oy = t2 % OH;
    int n = t2 / OH;

    const float* xn = x + (size_t)n * IC * IH * IW;
    float acc[OC];
#pragma unroll
    for (int oc = 0; oc < OC; oc++) acc[oc] = b[oc];

#pragma unroll 2
    for (int ic = 0; ic < IC; ic++) {
        float xv[9];
#pragma unroll
        for (int ky = 0; ky < 3; ky++) {
            int iy = 2 * oy - 1 + ky;
#pragma unroll
            for (int kx = 0; kx < 3; kx++) {
                int ix = 2 * ox - 1 + kx;
                bool ok = (iy >= 0) && (iy < IH) && (ix >= 0) && (ix < IW);
                xv[ky * 3 + kx] = ok ? xn[((size_t)ic * IH + iy) * IW + ix] : 0.f;
            }
        }
#pragma unroll
        for (int t3 = 0; t3 < 9; t3++) {
            if constexpr (OC % 4 == 0) {
                const float4* wr = (const float4*)(wlds + ((size_t)ic * 9 + t3) * OC);
#pragma unroll
                for (int o4 = 0; o4 < OC / 4; o4++) {
                    float4 wv = wr[o4];
                    acc[4 * o4 + 0] = fmaf(xv[t3], wv.x, acc[4 * o4 + 0]);
                    acc[4 * o4 + 1] = fmaf(xv[t3], wv.y, acc[4 * o4 + 1]);
                    acc[4 * o4 + 2] = fmaf(xv[t3], wv.z, acc[4 * o4 + 2]);
                    acc[4 * o4 + 3] = fmaf(xv[t3], wv.w, acc[4 * o4 + 3]);
                }
            } else {
#pragma unroll
                for (int oc = 0; oc < OC; oc++)
                    acc[oc] = fmaf(xv[t3], wlds[(ic * 9 + t3) * OC + oc], acc[oc]);
            }
        }
    }
    float* yn = y + (size_t)n * OC * OH * OW + (size_t)oy * OW + ox;
#pragma unroll
    for (int oc = 0; oc < OC; oc++) yn[(size_t)oc * OH * OW] = fmaxf(acc[oc], 0.f);
}

// ------------- deconv, full 2x2 parity fuse + oc split (dc1, dc2) ----------
template <int IC, int OC, int OCH, int IH>
__global__ __launch_bounds__(256, 2) void deconv_full_k(const float* __restrict__ x,
                                                        const float* __restrict__ w,
                                                        const float* __restrict__ bias,
                                                        float* __restrict__ y, int B) {
    constexpr int IW = IH, OH = 2 * IH, OW = 2 * IH;
    __shared__ float wlds[IC * 9 * OCH];  // [ic][tap][oc]
    const int ocb = blockIdx.y * OCH;
    for (int t = threadIdx.x; t < IC * 9 * OCH; t += blockDim.x) {
        int oc = t % OCH;
        int r = t / OCH;
        int tap = r % 9;
        int ic = r / 9;
        wlds[t] = w[((size_t)(ic * OC + ocb + oc)) * 9 + tap];
    }
    __syncthreads();

    int idx = blockIdx.x * blockDim.x + threadIdx.x;
    if (idx >= B * IH * IW) return;
    int j = idx % IW;
    int t2 = idx / IW;
    int i = t2 % IH;
    int n = t2 / IH;

    const float* xn = x + (size_t)n * IC * IH * IW;
    float acc[2][2][OCH];
#pragma unroll
    for (int oc = 0; oc < OCH; oc++) {
        float bv = bias[ocb + oc];
        acc[0][0][oc] = bv;
        acc[0][1][oc] = bv;
        acc[1][0][oc] = bv;
        acc[1][1][oc] = bv;
    }
    const bool jok = (j + 1 < IW);

    constexpr int EDY[9] = {0, 0, 0, 0, 0, 0, 1, 1, 1};
    constexpr int EDX[9] = {0, 0, 0, 0, 1, 1, 0, 0, 1};
    constexpr int ERY[9] = {0, 0, 1, 1, 0, 1, 1, 1, 1};
    constexpr int ERX[9] = {0, 1, 0, 1, 1, 1, 0, 1, 1};
    constexpr int ETAP[9] = {4, 5, 7, 8, 3, 6, 1, 2, 0};  // ky*3+kx

#pragma unroll 2
    for (int ic = 0; ic < IC; ic++) {
        const float* r0p = xn + ((size_t)ic * IH + i) * IW + j;
        const bool iok = (i + 1 < IH);
        float xv[2][2];
        xv[0][0] = r0p[0];
        xv[0][1] = jok ? r0p[1] : 0.f;
        xv[1][0] = iok ? r0p[IW] : 0.f;
        xv[1][1] = (iok && jok) ? r0p[IW + 1] : 0.f;
#pragma unroll
        for (int e = 0; e < 9; e++) {
            float xval = xv[EDY[e]][EDX[e]];
            const float4* wr = (const float4*)(wlds + ((size_t)ic * 9 + ETAP[e]) * OCH);
#pragma unroll
            for (int o4 = 0; o4 < OCH / 4; o4++) {
                float4 wv = wr[o4];
                acc[ERY[e]][ERX[e]][4 * o4 + 0] = fmaf(xval, wv.x, acc[ERY[e]][ERX[e]][4 * o4 + 0]);
                acc[ERY[e]][ERX[e]][4 * o4 + 1] = fmaf(xval, wv.y, acc[ERY[e]][ERX[e]][4 * o4 + 1]);
                acc[ERY[e]][ERX[e]][4 * o4 + 2] = fmaf(xval, wv.z, acc[ERY[e]][ERX[e]][4 * o4 + 2]);
                acc[ERY[e]][ERX[e]][4 * o4 + 3] = fmaf(xval, wv.w, acc[ERY[e]][ERX[e]][4 * o4 + 3]);
            }
        }
    }
    float* yb = y + ((size_t)(n * OC + ocb) * OH + 2 * i) * OW + 2 * j;
#pragma unroll
    for (int oc = 0; oc < OCH; oc++) {
        float* yp = yb + (size_t)oc * OH * OW;
        *reinterpret_cast<float2*>(yp) = make_float2(acc[0][0][oc], acc[0][1][oc]);
        *reinterpret_cast<float2*>(yp + OW) = make_float2(acc[1][0][oc], acc[1][1][oc]);
    }
}

// ---------------- dc3 weight repack: [ic][oc][9] -> [ic][oc][12] -----------
__global__ __launch_bounds__(256) void repack3_k(const float* __restrict__ w,
                                                 float* __restrict__ dst) {
    int idx = blockIdx.x * blockDim.x + threadIdx.x;  // over 32*64*9
    if (idx >= 32 * 64 * 9) return;
    int t = idx % 9;
    int r = idx / 9;  // ic*64+oc
    dst[r * 12 + t] = w[idx];
}

// ------------- dc3 (32->64 @ 32x32): wave per (n,i), lane = oc -------------
__global__ __launch_bounds__(256, 2) void deconv3_k(const float* __restrict__ x,    // [B,32,32,32]
                                                    const float* __restrict__ wrp,  // [32][64][12]
                                                    const float* __restrict__ bias,
                                                    float* __restrict__ y,          // [B,64,64,64]
                                                    int B) {
    constexpr int IC = 32, IH = 32, IW = 32, OC = 64, OH = 64, OW = 64;
    const int lane = threadIdx.x & 63;
    const int wv = __builtin_amdgcn_readfirstlane(threadIdx.x >> 6);
    const int row = blockIdx.x * 4 + wv;  // (n,i)
    const int n = row >> 5;
    const int i = row & 31;
    if (n >= B) return;

    float acc[2][OW];
    const float bv = bias[lane];
#pragma unroll
    for (int c = 0; c < OW; c++) {
        acc[0][c] = bv;
        acc[1][c] = bv;
    }

    const float* xb = x + ((size_t)n * IC * IH + i) * IW;
    const bool rok = (i + 1 < IH);

    for (int ic = 0; ic < IC; ic++) {
        const float* xr = xb + (size_t)ic * IH * IW;  // row i of plane ic (uniform addr)
        float x0[IW];
#pragma unroll
        for (int j = 0; j < IW; j++) x0[j] = xr[j];

        const float* wl = wrp + ((size_t)ic * OC + lane) * 12;
        float w[9];
#pragma unroll
        for (int t = 0; t < 9; t++) w[t] = wl[t];

        // rcA: x row i, ky=1 -> out row 2i ; rcB: x row i, ky=2 -> out row 2i+1
#pragma unroll
        for (int j = 0; j < IW; j++) {
            acc[0][2 * j] = fmaf(x0[j], w[4], acc[0][2 * j]);
            acc[0][2 * j + 1] = fmaf(x0[j], w[5], acc[0][2 * j + 1]);
            acc[1][2 * j] = fmaf(x0[j], w[7], acc[1][2 * j]);
            acc[1][2 * j + 1] = fmaf(x0[j], w[8], acc[1][2 * j + 1]);
            if (j >= 1) {
                acc[0][2 * j - 1] = fmaf(x0[j], w[3], acc[0][2 * j - 1]);
                acc[1][2 * j - 1] = fmaf(x0[j], w[6], acc[1][2 * j - 1]);
            }
        }
        // rcC: x row i+1, ky=0 -> out row 2i+1
        if (rok) {
            float x1[IW];
#pragma unroll
            for (int j = 0; j < IW; j++) x1[j] = xr[IW + j];
#pragma unroll
            for (int j = 0; j < IW; j++) {
                acc[1][2 * j] = fmaf(x1[j], w[1], acc[1][2 * j]);
                acc[1][2 * j + 1] = fmaf(x1[j], w[2], acc[1][2 * j + 1]);
                if (j >= 1) acc[1][2 * j - 1] = fmaf(x1[j], w[0], acc[1][2 * j - 1]);
            }
        }
    }

    float* yb = y + ((size_t)(n * OC + lane) * OH + 2 * i) * OW;
#pragma unroll
    for (int r = 0; r < 2; r++)
#pragma unroll
        for (int c4 = 0; c4 < OW / 4; c4++)
            *reinterpret_cast<float4*>(yb + r * OW + 4 * c4) =
                make_float4(acc[r][4 * c4], acc[r][4 * c4 + 1], acc[r][4 * c4 + 2],
                            acc[r][4 * c4 + 3]);
}

// ----------- deconv final (dc4: 64->3@64), OC padded to 4, 2-col -----------
__global__ __launch_bounds__(256, 4) void deconv_last_k(const float* __restrict__ x,
                                                        const float* __restrict__ w,
                                                        const float* __restrict__ bias,
                                                        float* __restrict__ y, int B) {
    constexpr int IC = 64, OCR = 3, IH = 64, IW = 64, OH = 128, OW = 128, JP = 32;
    __shared__ float wlds[IC * 9 * 4];  // [ic][tap][oc4]
    for (int t = threadIdx.x; t < IC * 9 * 4; t += blockDim.x) {
        int oc = t % 4;
        int rest = t / 4;
        int tap = rest % 9;
        int ic = rest / 9;
        wlds[t] = (oc < OCR) ? w[(ic * OCR + oc) * 9 + tap] : 0.f;
    }
    __syncthreads();

    int idx = blockIdx.x * blockDim.x + threadIdx.x;
    if (idx >= B * IH * JP) return;
    int jp = idx % JP;
    int t2 = idx / JP;
    int i = t2 % IH;
    int n = t2 / IH;

    const float* xn = x + (size_t)n * IC * IH * IW + 2 * jp;
    float b0 = bias[0], b1 = bias[1], b2 = bias[2];
    float acc[2][4][4];  // [ry][out col][oc4]
#pragma unroll
    for (int ry = 0; ry < 2; ry++)
#pragma unroll
        for (int c = 0; c < 4; c++) {
            acc[ry][c][0] = b0;
            acc[ry][c][1] = b1;
            acc[ry][c][2] = b2;
            acc[ry][c][3] = 0.f;
        }
    const bool jok = (jp + 1 < JP);

    constexpr int RDY[3] = {0, 0, 1};
    constexpr int RRY[3] = {0, 1, 1};
    constexpr int RKY[3] = {1, 2, 0};

#pragma unroll 4
    for (int ic = 0; ic < IC; ic++) {
        float xr[2][3];
#pragma unroll
        for (int r = 0; r < 2; r++) {
            const float* rp = xn + ((size_t)ic * IH + i + r) * IW;
            bool rok = (r == 0) || (i + 1 < IH);
            xr[r][0] = rok ? rp[0] : 0.f;
            xr[r][1] = rok ? rp[1] : 0.f;
            xr[r][2] = (rok && jok) ? rp[2] : 0.f;
        }
        const float4* w4 = (const float4*)(wlds) + ic * 9;
#pragma unroll
        for (int rc = 0; rc < 3; rc++) {
            float4 W0 = w4[RKY[rc] * 3 + 0];
            float4 W1 = w4[RKY[rc] * 3 + 1];
            float4 W2 = w4[RKY[rc] * 3 + 2];
            float x0 = xr[RDY[rc]][0], x1 = xr[RDY[rc]][1], x2 = xr[RDY[rc]][2];
#define QQ(c, xa, Wv)                                            \
    {                                                            \
        acc[RRY[rc]][c][0] = fmaf(xa, Wv.x, acc[RRY[rc]][c][0]); \
        acc[RRY[rc]][c][1] = fmaf(xa, Wv.y, acc[RRY[rc]][c][1]); \
        acc[RRY[rc]][c][2] = fmaf(xa, Wv.z, acc[RRY[rc]][c][2]); \
        acc[RRY[rc]][c][3] = fmaf(xa, Wv.w, acc[RRY[rc]][c][3]); \
    }
            QQ(0, x0, W1)
            QQ(1, x0, W2)
            QQ(1, x1, W0)
            QQ(2, x1, W1)
            QQ(3, x1, W2)
            QQ(3, x2, W0)
#undef QQ
        }
    }
#pragma unroll
    for (int oc = 0; oc < OCR; oc++) {
        float* yp = y + ((size_t)(n * OCR + oc) * OH + 2 * i) * OW + 4 * jp;
        *reinterpret_cast<float4*>(yp) =
            make_float4(acc[0][0][oc], acc[0][1][oc], acc[0][2][oc], acc[0][3][oc]);
        *reinterpret_cast<float4*>(yp + OW) =
            make_float4(acc[1][0][oc], acc[1][1][oc], acc[1][2][oc], acc[1][3][oc]);
    }
}

// ------------------------------ linear (+act) ------------------------------
template <int IN, int OUT, int ACT>  // ACT: 0 relu, 1 leaky(0.01)
__global__ __launch_bounds__(256) void linear_k(const float* __restrict__ h,
                                                const float* __restrict__ w,
                                                const float* __restrict__ b,
                                                float* __restrict__ y, int B) {
    int idx = blockIdx.x * blockDim.x + threadIdx.x;
    if (idx >= B * OUT) return;
    int o = idx % OUT;
    int n = idx / OUT;
    const float4* hr = (const float4*)(h + (size_t)n * IN);
    const float4* wr = (const float4*)(w + (size_t)o * IN);
    float acc = 0.f;
#pragma unroll 4
    for (int k = 0; k < IN / 4; k++) {
        float4 a = hr[k];
        float4 ww = wr[k];
        acc += a.x * ww.x + a.y * ww.y + a.z * ww.z + a.w * ww.w;
    }
    acc += b[o];
    y[idx] = (ACT == 0) ? fmaxf(acc, 0.f) : (acc > 0.f ? acc : 0.01f * acc);
}

// --------------------- CustomLayer: lin + tanh neuron ----------------------
__global__ __launch_bounds__(256) void custom_layer_k(
    const float* __restrict__ h, const float* __restrict__ clw, const float* __restrict__ clb,
    const float* __restrict__ nw, const float* __restrict__ nb, const float* __restrict__ low,
    const float* __restrict__ high, float* __restrict__ y, int B) {
    int idx = blockIdx.x * blockDim.x + threadIdx.x;
    if (idx >= B * 512) return;
    int o = idx % 512;
    int n = idx / 512;
    const float4* hr = (const float4*)(h + (size_t)n * 256);
    const float4* w1 = (const float4*)(clw + (size_t)o * 256);
    const float4* w2 = (const float4*)(nw + (size_t)o * 256);
    float lin = 0.f, z = 0.f;
#pragma unroll 4
    for (int k = 0; k < 64; k++) {
        float4 a = hr[k];
        float4 b1 = w1[k];
        float4 b2 = w2[k];
        lin += a.x * b1.x + a.y * b1.y + a.z * b1.z + a.w * b1.w;
        z += a.x * b2.x + a.y * b2.y + a.z * b2.z + a.w * b2.w;
    }
    lin += clb[o];
    z += nb[o];
    float neur = tanhf(tanhf(low[o] * z - high[o]));
    y[idx] = fmaxf(lin + neur, 0.f);
}

// ---------------------------------------------------------------------------
extern "C" void kernel_launch(void* const* d_in, const int* in_sizes, int n_in,
                              void* d_out, int out_size, void* d_ws, size_t ws_size,
                              hipStream_t stream) {
    const float* x = (const float*)d_in[0];
    const float* conv1_w = (const float*)d_in[1];
    const float* conv1_b = (const float*)d_in[2];
    const float* conv2_w = (const float*)d_in[3];
    const float* conv2_b = (const float*)d_in[4];
    const float* conv3_w = (const float*)d_in[5];
    const float* conv3_b = (const float*)d_in[6];
    const float* conv4_w = (const float*)d_in[7];
    const float* conv4_b = (const float*)d_in[8];
    const float* l2_w = (const float*)d_in[9];
    const float* l2_b = (const float*)d_in[10];
    const float* cl_w = (const float*)d_in[11];
    const float* cl_b = (const float*)d_in[12];
    const float* n_w = (const float*)d_in[13];
    const float* n_b = (const float*)d_in[14];
    const float* low = (const float*)d_in[15];
    const float* high = (const float*)d_in[16];
    const float* l4_w = (const float*)d_in[17];
    const float* l4_b = (const float*)d_in[18];
    const float* lL_w = (const float*)d_in[19];
    const float* lL_b = (const float*)d_in[20];
    const float* fc4_w = (const float*)d_in[21];
    const float* fc4_b = (const float*)d_in[22];
    const float* fc5_w = (const float*)d_in[23];
    const float* fc5_b = (const float*)d_in[24];
    const float* dc1_w = (const float*)d_in[25];
    const float* dc1_b = (const float*)d_in[26];
    const float* dc2_w = (const float*)d_in[27];
    const float* dc2_b = (const float*)d_in[28];
    const float* dc3_w = (const float*)d_in[29];
    const float* dc3_b = (const float*)d_in[30];
    const float* dc4_w = (const float*)d_in[31];
    const float* dc4_b = (const float*)d_in[32];

    const int B = in_sizes[0] / (3 * 128 * 128);  // 256
    float* out = (float*)d_out;
    float* ws = (float*)d_ws;

    // ---- ws layout (peak ~141 MB; known safe: r3 ran with 172.5 MB) ----
    float* rp3 = ws;                      // 32*64*12 = 24576 floats
    float* h4 = rp3 + 24576;              // [B,128]
    float* h5 = h4 + (size_t)B * 128;     // [B,256]
    float* h6 = h5 + (size_t)B * 256;     // [B,512]
    float* h7 = h6 + (size_t)B * 512;     // [B,256]
    float* h8 = h7 + (size_t)B * 256;     // [B,256]
    float* h9 = h8 + (size_t)B * 256;     // [B,512]
    float* h10 = h9 + (size_t)B * 512;    // [B,512]
    float* Rb = h10 + (size_t)B * 512;    // big region
    // encoder phase:
    float* h1 = Rb;                        // [B,16,64,64] = B*65536
    float* h2 = h1 + (size_t)B * 65536;    // [B,8,32,32]  = B*8192
    float* h3 = h2 + (size_t)B * 8192;     // [B,4,16,16]  = B*1024
    // decoder phase (encoder buffers dead):
    float* d1 = Rb;                        // [B,16,16,16] = B*4096
    float* d3buf = Rb + (size_t)B * 4096;  // [B/2,64,64,64] = (B/2)*262144
    // d2 lives in the tail of d_out: [B,32,32,32] = B*32768 floats
    float* d2 = out + (size_t)B * (49152 - 32768);

    dim3 blk(256);
    auto cdiv = [](int a, int b) { return (a + b - 1) / b; };

    // dc3 weight repack
    repack3_k<<<dim3(cdiv(32 * 64 * 9, 256)), blk, 0, stream>>>(dc3_w, rp3);

    // ---------------- encoder, full batch ----------------
    conv_k<3, 16, 128, 128><<<dim3(cdiv(B * 64 * 64, 256)), blk, 0, stream>>>(x, conv1_w, conv1_b,
                                                                              h1, B);
    conv_k<16, 8, 64, 64><<<dim3(cdiv(B * 32 * 32, 256)), blk, 0, stream>>>(h1, conv2_w, conv2_b,
                                                                            h2, B);
    conv_k<8, 4, 32, 32><<<dim3(cdiv(B * 16 * 16, 256)), blk, 0, stream>>>(h2, conv3_w, conv3_b,
                                                                           h3, B);
    conv_k<4, 2, 16, 16><<<dim3(cdiv(B * 8 * 8, 256)), blk, 0, stream>>>(h3, conv4_w, conv4_b, h4,
                                                                         B);

    // ---------------- FC chain, full batch ----------------
    linear_k<128, 256, 0><<<dim3(cdiv(B * 256, 256)), blk, 0, stream>>>(h4, l2_w, l2_b, h5, B);
    custom_layer_k<<<dim3(cdiv(B * 512, 256)), blk, 0, stream>>>(h5, cl_w, cl_b, n_w, n_b, low,
                                                                 high, h6, B);
    linear_k<512, 256, 0><<<dim3(cdiv(B * 256, 256)), blk, 0, stream>>>(h6, l4_w, l4_b, h7, B);
    linear_k<256, 256, 1><<<dim3(cdiv(B * 256, 256)), blk, 0, stream>>>(h7, lL_w, lL_b, h8, B);
    linear_k<256, 512, 1><<<dim3(cdiv(B * 512, 256)), blk, 0, stream>>>(h8, fc4_w, fc4_b, h9, B);
    linear_k<512, 512, 0><<<dim3(cdiv(B * 512, 256)), blk, 0, stream>>>(h9, fc5_w, fc5_b, h10, B);

    // ---------------- decoder ----------------
    // dc1: [B,8,8,8] -> d1 [B,16,16,16], full batch, oc split x2
    deconv_full_k<8, 16, 8, 8><<<dim3(cdiv(B * 64, 256), 2), blk, 0, stream>>>(h10, dc1_w, dc1_b,
                                                                               d1, B);
    // dc2: d1 -> d2 (in d_out tail) [B,32,32,32], full batch, oc split x2
    deconv_full_k<16, 32, 16, 16><<<dim3(cdiv(B * 256, 256), 2), blk, 0, stream>>>(d1, dc2_w,
                                                                                   dc2_b, d2, B);
    // dc3+dc4 chunked over batch halves (d3buf holds B/2 samples).
    // Sequencing: out-chunk c only overwrites d2 chunks <= c (already consumed).
    const int HB = B / 2;
    for (int c = 0; c < 2; c++) {
        const float* d2c = d2 + (size_t)c * HB * 32768;
        deconv3_k<<<dim3(HB * 32 / 4), blk, 0, stream>>>(d2c, rp3, dc3_b, d3buf, HB);
        deconv_last_k<<<dim3(cdiv(HB * 64 * 32, 256)), blk, 0, stream>>>(
            d3buf, dc4_w, dc4_b, out + (size_t)c * HB * 49152, HB);
    }
}